// Round 1
// baseline (3437.017 us; speedup 1.0000x reference)
//
#include <hip/hip_runtime.h>
#include <math.h>

#define N_NODES 100000
#define N_EDGES 1600000
#define NEG_SLOPE 0.2f

// ---------------- layer 1: node transform -------------------------------
// h1 = x @ W1  (x:[N,5], W1:[5,64]) ; as1/ad1 per-head attention dots.
// 8 threads per node, one head each.
__global__ void k_node1(const float* __restrict__ x, const float* __restrict__ W1,
                        const float* __restrict__ a_src1, const float* __restrict__ a_dst1,
                        float* __restrict__ h1, float* __restrict__ as1,
                        float* __restrict__ ad1) {
    int tid  = blockIdx.x * blockDim.x + threadIdx.x;
    int n    = tid >> 3;
    int head = tid & 7;
    if (n >= N_NODES) return;

    float xv[5];
#pragma unroll
    for (int k = 0; k < 5; ++k) xv[k] = x[n * 5 + k];

    float hv[8];
    float as = 0.f, ad = 0.f;
#pragma unroll
    for (int j = 0; j < 8; ++j) {
        int c = head * 8 + j;
        float acc = 0.f;
#pragma unroll
        for (int k = 0; k < 5; ++k) acc += xv[k] * W1[k * 64 + c];
        hv[j] = acc;
        as += acc * a_src1[c];
        ad += acc * a_dst1[c];
    }
    float4* hp = (float4*)&h1[n * 64 + head * 8];
    hp[0] = make_float4(hv[0], hv[1], hv[2], hv[3]);
    hp[1] = make_float4(hv[4], hv[5], hv[6], hv[7]);
    as1[n * 8 + head] = as;
    ad1[n * 8 + head] = ad;
}

// ---------------- layer 1: edge scatter ---------------------------------
// thread per (edge, head). w = exp(leaky_relu(as[s]+ad[d]))
// num[d] += w*h1[s], den[d] += w   (softmax normalization deferred to node pass)
__global__ void k_edge1(const int* __restrict__ src, const int* __restrict__ dst,
                        const float* __restrict__ h1, const float* __restrict__ as1,
                        const float* __restrict__ ad1, float* __restrict__ num1,
                        float* __restrict__ den1) {
    int tid  = blockIdx.x * blockDim.x + threadIdx.x;
    int e    = tid >> 3;
    int head = tid & 7;
    if (e >= N_EDGES + N_NODES) return;

    int s, d;
    if (e < N_EDGES) { s = src[e]; d = dst[e]; }
    else             { s = e - N_EDGES; d = s; }   // self-loop

    float t = as1[s * 8 + head] + ad1[d * 8 + head];
    t = (t > 0.f) ? t : NEG_SLOPE * t;
    float w = __expf(t);

    atomicAdd(&den1[d * 8 + head], w);

    const float4* hp = (const float4*)&h1[s * 64 + head * 8];
    float4 a = hp[0];
    float4 b = hp[1];
    float* np = &num1[d * 64 + head * 8];
    atomicAdd(np + 0, w * a.x);
    atomicAdd(np + 1, w * a.y);
    atomicAdd(np + 2, w * a.z);
    atomicAdd(np + 3, w * a.w);
    atomicAdd(np + 4, w * b.x);
    atomicAdd(np + 5, w * b.y);
    atomicAdd(np + 6, w * b.z);
    atomicAdd(np + 7, w * b.w);
}

// ---------------- layer 1 epilogue + layer 2 node transform -------------
// out1 = elu(num/den + b1); h2 = out1 @ W2 (64->2); as2/ad2 scalars.
__global__ void k_node2(const float* __restrict__ num1, const float* __restrict__ den1,
                        const float* __restrict__ b1, const float* __restrict__ W2,
                        const float* __restrict__ a_src2, const float* __restrict__ a_dst2,
                        float* __restrict__ h2, float* __restrict__ as2,
                        float* __restrict__ ad2) {
    int n = blockIdx.x * blockDim.x + threadIdx.x;
    if (n >= N_NODES) return;

    float invd[8];
#pragma unroll
    for (int h = 0; h < 8; ++h) invd[h] = 1.f / den1[n * 8 + h];

    float h20 = 0.f, h21 = 0.f;
#pragma unroll
    for (int c = 0; c < 64; ++c) {
        float v = num1[n * 64 + c] * invd[c >> 3] + b1[c];
        v = (v > 0.f) ? v : (__expf(v) - 1.f);     // ELU
        h20 += v * W2[c * 2 + 0];
        h21 += v * W2[c * 2 + 1];
    }
    h2[n * 2 + 0] = h20;
    h2[n * 2 + 1] = h21;
    as2[n] = h20 * a_src2[0] + h21 * a_src2[1];
    ad2[n] = h20 * a_dst2[0] + h21 * a_dst2[1];
}

// ---------------- layer 2: edge scatter ---------------------------------
__global__ void k_edge2(const int* __restrict__ src, const int* __restrict__ dst,
                        const float* __restrict__ h2, const float* __restrict__ as2,
                        const float* __restrict__ ad2, float* __restrict__ num2,
                        float* __restrict__ den2) {
    int e = blockIdx.x * blockDim.x + threadIdx.x;
    if (e >= N_EDGES + N_NODES) return;

    int s, d;
    if (e < N_EDGES) { s = src[e]; d = dst[e]; }
    else             { s = e - N_EDGES; d = s; }

    float t = as2[s] + ad2[d];
    t = (t > 0.f) ? t : NEG_SLOPE * t;
    float w = __expf(t);

    atomicAdd(&den2[d], w);
    atomicAdd(&num2[d * 2 + 0], w * h2[s * 2 + 0]);
    atomicAdd(&num2[d * 2 + 1], w * h2[s * 2 + 1]);
}

// ---------------- layer 2 epilogue: log_softmax -------------------------
__global__ void k_out(const float* __restrict__ num2, const float* __restrict__ den2,
                      const float* __restrict__ b2, float* __restrict__ out) {
    int n = blockIdx.x * blockDim.x + threadIdx.x;
    if (n >= N_NODES) return;
    float invd = 1.f / den2[n];
    float o0 = num2[n * 2 + 0] * invd + b2[0];
    float o1 = num2[n * 2 + 1] * invd + b2[1];
    float m  = fmaxf(o0, o1);
    float lse = m + __logf(__expf(o0 - m) + __expf(o1 - m));
    out[n * 2 + 0] = o0 - lse;
    out[n * 2 + 1] = o1 - lse;
}

extern "C" void kernel_launch(void* const* d_in, const int* in_sizes, int n_in,
                              void* d_out, int out_size, void* d_ws, size_t ws_size,
                              hipStream_t stream) {
    const float* x      = (const float*)d_in[0];
    const int*   ei     = (const int*)d_in[1];     // [2, E] int32
    const float* W1     = (const float*)d_in[2];
    const float* a_src1 = (const float*)d_in[3];
    const float* a_dst1 = (const float*)d_in[4];
    const float* b1     = (const float*)d_in[5];
    const float* W2     = (const float*)d_in[6];
    const float* a_src2 = (const float*)d_in[7];
    const float* a_dst2 = (const float*)d_in[8];
    const float* b2     = (const float*)d_in[9];
    float* out = (float*)d_out;

    const int* src = ei;
    const int* dst = ei + N_EDGES;

    // workspace layout (floats). Accumulators first so one memset covers them.
    float* ws   = (float*)d_ws;
    float* num1 = ws;                       // N*64
    float* den1 = num1 + N_NODES * 64;      // N*8
    float* num2 = den1 + N_NODES * 8;       // N*2
    float* den2 = num2 + N_NODES * 2;       // N*1   -> accum total N*75
    float* h1   = den2 + N_NODES;           // N*64
    float* as1  = h1 + N_NODES * 64;        // N*8
    float* ad1  = as1 + N_NODES * 8;        // N*8
    float* h2   = ad1 + N_NODES * 8;        // N*2
    float* as2  = h2 + N_NODES * 2;         // N
    float* ad2  = as2 + N_NODES;            // N

    hipMemsetAsync(ws, 0, (size_t)N_NODES * 75 * sizeof(float), stream);

    {
        int threads = N_NODES * 8;
        k_node1<<<(threads + 255) / 256, 256, 0, stream>>>(x, W1, a_src1, a_dst1,
                                                           h1, as1, ad1);
    }
    {
        long long threads = (long long)(N_EDGES + N_NODES) * 8;
        k_edge1<<<(int)((threads + 255) / 256), 256, 0, stream>>>(src, dst, h1, as1,
                                                                  ad1, num1, den1);
    }
    k_node2<<<(N_NODES + 255) / 256, 256, 0, stream>>>(num1, den1, b1, W2, a_src2,
                                                       a_dst2, h2, as2, ad2);
    {
        int threads = N_EDGES + N_NODES;
        k_edge2<<<(threads + 255) / 256, 256, 0, stream>>>(src, dst, h2, as2, ad2,
                                                           num2, den2);
    }
    k_out<<<(N_NODES + 255) / 256, 256, 0, stream>>>(num2, den2, b2, out);
}

// Round 2
// 662.019 us; speedup vs baseline: 5.1917x; 5.1917x over previous
//
#include <hip/hip_runtime.h>
#include <math.h>

#define N_NODES 100000
#define N_EDGES 1600000
#define N_TOT   (N_EDGES + N_NODES)   // edges + self-loops
#define NEG_SLOPE 0.2f

// ---------------- layer 1: node transform -------------------------------
// h1 = x @ W1 (x:[N,5], W1:[5,64]); as1/ad1 per-head attention dots.
// 8 threads per node, one head each.
__global__ void k_node1(const float* __restrict__ x, const float* __restrict__ W1,
                        const float* __restrict__ a_src1, const float* __restrict__ a_dst1,
                        float* __restrict__ h1, float* __restrict__ as1,
                        float* __restrict__ ad1) {
    int tid  = blockIdx.x * blockDim.x + threadIdx.x;
    int n    = tid >> 3;
    int head = tid & 7;
    if (n >= N_NODES) return;

    float xv[5];
#pragma unroll
    for (int k = 0; k < 5; ++k) xv[k] = x[n * 5 + k];

    float hv[8];
    float as = 0.f, ad = 0.f;
#pragma unroll
    for (int j = 0; j < 8; ++j) {
        int c = head * 8 + j;
        float acc = 0.f;
#pragma unroll
        for (int k = 0; k < 5; ++k) acc += xv[k] * W1[k * 64 + c];
        hv[j] = acc;
        as += acc * a_src1[c];
        ad += acc * a_dst1[c];
    }
    float4* hp = (float4*)&h1[n * 64 + head * 8];
    hp[0] = make_float4(hv[0], hv[1], hv[2], hv[3]);
    hp[1] = make_float4(hv[4], hv[5], hv[6], hv[7]);
    as1[n * 8 + head] = as;
    ad1[n * 8 + head] = ad;
}

// ---------------- CSR build: histogram of dst ---------------------------
__global__ void k_hist(const int* __restrict__ dst, int* __restrict__ count) {
    int t = blockIdx.x * blockDim.x + threadIdx.x;
    if (t >= N_TOT) return;
    int d = (t < N_EDGES) ? dst[t] : (t - N_EDGES);
    atomicAdd(&count[d], 1);
}

// ---------------- CSR build: exclusive scan (single block) --------------
// 1024 threads, each owns 98 consecutive counters.
#define SCAN_CHUNK 98
__global__ void k_scan(const int* __restrict__ count, int* __restrict__ rowptr) {
    __shared__ int sm[1024];
    int t = threadIdx.x;
    int base = t * SCAN_CHUNK;
    int local = 0;
    for (int i = 0; i < SCAN_CHUNK; ++i) {
        int idx = base + i;
        if (idx < N_NODES) local += count[idx];
    }
    sm[t] = local;
    __syncthreads();
    for (int off = 1; off < 1024; off <<= 1) {
        int v = (t >= off) ? sm[t - off] : 0;
        __syncthreads();
        sm[t] += v;
        __syncthreads();
    }
    int run = sm[t] - local;   // exclusive start of this thread's range
    for (int i = 0; i < SCAN_CHUNK; ++i) {
        int idx = base + i;
        if (idx < N_NODES) { rowptr[idx] = run; run += count[idx]; }
    }
    if (t == 1023) rowptr[N_NODES] = sm[1023];
}

// ---------------- CSR build: scatter srcs into dst order ----------------
// atomicSub reuses the histogram as a reverse-fill cursor (no extra memset).
__global__ void k_scatter(const int* __restrict__ src, const int* __restrict__ dst,
                          const int* __restrict__ rowptr, int* __restrict__ count,
                          int* __restrict__ ssrc) {
    int t = blockIdx.x * blockDim.x + threadIdx.x;
    if (t >= N_TOT) return;
    int s, d;
    if (t < N_EDGES) { s = src[t]; d = dst[t]; }
    else             { s = t - N_EDGES; d = s; }
    int old = atomicSub(&count[d], 1);
    ssrc[rowptr[d] + old - 1] = s;
}

// ---------------- layer 1: per-dst gather + softmax + ELU ---------------
// One wave (64 lanes) per dst node; lane = output channel, head = lane>>3.
// No atomics: num/den accumulate in registers over the node's edge list.
__global__ void k_gather1(const int* __restrict__ rowptr, const int* __restrict__ ssrc,
                          const float* __restrict__ h1, const float* __restrict__ as1,
                          const float* __restrict__ ad1, const float* __restrict__ b1,
                          float* __restrict__ o1) {
    int gtid = blockIdx.x * blockDim.x + threadIdx.x;
    int d    = gtid >> 6;
    int lane = threadIdx.x & 63;
    if (d >= N_NODES) return;
    int head = lane >> 3;

    int beg = rowptr[d], end = rowptr[d + 1];
    float adv = ad1[d * 8 + head];
    float num = 0.f, den = 0.f;
    for (int k = beg; k < end; ++k) {
        int s = ssrc[k];                       // wave-uniform broadcast
        float t = as1[s * 8 + head] + adv;
        t = (t > 0.f) ? t : NEG_SLOPE * t;
        float w = __expf(t);
        num += w * h1[s * 64 + lane];          // coalesced 256B per edge
        den += w;
    }
    float v = num / den + b1[lane];
    v = (v > 0.f) ? v : (__expf(v) - 1.f);     // ELU
    o1[d * 64 + lane] = v;
}

// ---------------- layer 2 node transform --------------------------------
// h2 = o1 @ W2 (64->2); as2/ad2 scalars.
__global__ void k_node2(const float* __restrict__ o1, const float* __restrict__ W2,
                        const float* __restrict__ a_src2, const float* __restrict__ a_dst2,
                        float* __restrict__ h2, float* __restrict__ as2,
                        float* __restrict__ ad2) {
    int n = blockIdx.x * blockDim.x + threadIdx.x;
    if (n >= N_NODES) return;

    float h20 = 0.f, h21 = 0.f;
    const float4* op = (const float4*)&o1[n * 64];
#pragma unroll
    for (int q = 0; q < 16; ++q) {
        float4 v = op[q];
        int c = q * 4;
        h20 += v.x * W2[(c + 0) * 2] + v.y * W2[(c + 1) * 2] +
               v.z * W2[(c + 2) * 2] + v.w * W2[(c + 3) * 2];
        h21 += v.x * W2[(c + 0) * 2 + 1] + v.y * W2[(c + 1) * 2 + 1] +
               v.z * W2[(c + 2) * 2 + 1] + v.w * W2[(c + 3) * 2 + 1];
    }
    h2[n * 2 + 0] = h20;
    h2[n * 2 + 1] = h21;
    as2[n] = h20 * a_src2[0] + h21 * a_src2[1];
    ad2[n] = h20 * a_dst2[0] + h21 * a_dst2[1];
}

// ---------------- layer 2: per-dst gather + log_softmax -----------------
// One thread per dst node.
__global__ void k_gather2(const int* __restrict__ rowptr, const int* __restrict__ ssrc,
                          const float* __restrict__ h2, const float* __restrict__ as2,
                          const float* __restrict__ ad2, const float* __restrict__ b2,
                          float* __restrict__ out) {
    int d = blockIdx.x * blockDim.x + threadIdx.x;
    if (d >= N_NODES) return;

    int beg = rowptr[d], end = rowptr[d + 1];
    float adv = ad2[d];
    float n0 = 0.f, n1 = 0.f, den = 0.f;
    const float2* h2v = (const float2*)h2;
    for (int k = beg; k < end; ++k) {
        int s = ssrc[k];
        float t = as2[s] + adv;
        t = (t > 0.f) ? t : NEG_SLOPE * t;
        float w = __expf(t);
        float2 hv = h2v[s];
        n0 += w * hv.x;
        n1 += w * hv.y;
        den += w;
    }
    float o0 = n0 / den + b2[0];
    float o1 = n1 / den + b2[1];
    float m  = fmaxf(o0, o1);
    float lse = m + __logf(__expf(o0 - m) + __expf(o1 - m));
    out[d * 2 + 0] = o0 - lse;
    out[d * 2 + 1] = o1 - lse;
}

extern "C" void kernel_launch(void* const* d_in, const int* in_sizes, int n_in,
                              void* d_out, int out_size, void* d_ws, size_t ws_size,
                              hipStream_t stream) {
    const float* x      = (const float*)d_in[0];
    const int*   ei     = (const int*)d_in[1];     // [2, E] int32
    const float* W1     = (const float*)d_in[2];
    const float* a_src1 = (const float*)d_in[3];
    const float* a_dst1 = (const float*)d_in[4];
    const float* b1     = (const float*)d_in[5];
    const float* W2     = (const float*)d_in[6];
    const float* a_src2 = (const float*)d_in[7];
    const float* a_dst2 = (const float*)d_in[8];
    const float* b2     = (const float*)d_in[9];
    float* out = (float*)d_out;

    const int* src = ei;
    const int* dst = ei + N_EDGES;

    // ---- workspace layout ----
    int*   wi     = (int*)d_ws;
    int*   count  = wi;                         // N        (histogram, then cursor)
    int*   rowptr = count + N_NODES;            // N+1
    int*   ssrc   = rowptr + N_NODES + 1;       // E+N
    float* wf     = (float*)(ssrc + N_TOT);
    float* h1     = wf;                         // N*64
    float* as1    = h1  + (size_t)N_NODES * 64; // N*8
    float* ad1    = as1 + (size_t)N_NODES * 8;  // N*8
    float* o1     = ad1 + (size_t)N_NODES * 8;  // N*64
    float* h2     = o1  + (size_t)N_NODES * 64; // N*2
    float* as2    = h2  + (size_t)N_NODES * 2;  // N
    float* ad2    = as2 + (size_t)N_NODES;      // N

    // zero only the histogram (everything else is fully overwritten)
    hipMemsetAsync(count, 0, (size_t)N_NODES * sizeof(int), stream);

    k_node1<<<(N_NODES * 8 + 255) / 256, 256, 0, stream>>>(x, W1, a_src1, a_dst1,
                                                           h1, as1, ad1);
    k_hist<<<(N_TOT + 255) / 256, 256, 0, stream>>>(dst, count);
    k_scan<<<1, 1024, 0, stream>>>(count, rowptr);
    k_scatter<<<(N_TOT + 255) / 256, 256, 0, stream>>>(src, dst, rowptr, count, ssrc);
    k_gather1<<<(N_NODES * 64 + 255) / 256, 256, 0, stream>>>(rowptr, ssrc, h1, as1,
                                                              ad1, b1, o1);
    k_node2<<<(N_NODES + 255) / 256, 256, 0, stream>>>(o1, W2, a_src2, a_dst2,
                                                       h2, as2, ad2);
    k_gather2<<<(N_NODES + 255) / 256, 256, 0, stream>>>(rowptr, ssrc, h2, as2,
                                                         ad2, b2, out);
}

// Round 3
// 490.503 us; speedup vs baseline: 7.0071x; 1.3497x over previous
//
#include <hip/hip_runtime.h>
#include <math.h>

#define N_NODES 100000
#define N_EDGES 1600000
#define N_TOT   (N_EDGES + N_NODES)   // edges + self-loops
#define NEG_SLOPE 0.2f

#define SCAN_NBLK ((N_NODES + 1023) / 1024)   // 98 blocks, 1024 counters each

// ---------------- layer 1: node transform -------------------------------
// h1 = x @ W1 (x:[N,5], W1:[5,64]); as1/ad1 per-head attention dots.
// 8 threads per node, one head each.
__global__ void k_node1(const float* __restrict__ x, const float* __restrict__ W1,
                        const float* __restrict__ a_src1, const float* __restrict__ a_dst1,
                        float* __restrict__ h1, float* __restrict__ as1,
                        float* __restrict__ ad1) {
    int tid  = blockIdx.x * blockDim.x + threadIdx.x;
    int n    = tid >> 3;
    int head = tid & 7;
    if (n >= N_NODES) return;

    float xv[5];
#pragma unroll
    for (int k = 0; k < 5; ++k) xv[k] = x[n * 5 + k];

    float hv[8];
    float as = 0.f, ad = 0.f;
#pragma unroll
    for (int j = 0; j < 8; ++j) {
        int c = head * 8 + j;
        float acc = 0.f;
#pragma unroll
        for (int k = 0; k < 5; ++k) acc += xv[k] * W1[k * 64 + c];
        hv[j] = acc;
        as += acc * a_src1[c];
        ad += acc * a_dst1[c];
    }
    float4* hp = (float4*)&h1[n * 64 + head * 8];
    hp[0] = make_float4(hv[0], hv[1], hv[2], hv[3]);
    hp[1] = make_float4(hv[4], hv[5], hv[6], hv[7]);
    as1[n * 8 + head] = as;
    ad1[n * 8 + head] = ad;
}

// ---------------- CSR build: histogram of dst ---------------------------
__global__ void k_hist(const int* __restrict__ dst, int* __restrict__ count) {
    int t = blockIdx.x * blockDim.x + threadIdx.x;
    if (t >= N_TOT) return;
    int d = (t < N_EDGES) ? dst[t] : (t - N_EDGES);
    atomicAdd(&count[d], 1);
}

// ---------------- CSR build: hierarchical exclusive scan ----------------
// stage A: 98 blocks x 256 threads; each block scans 1024 counters in LDS,
// writes block-local exclusive prefixes into rowptr and its total to bsum.
__global__ void k_scan_a(const int* __restrict__ count, int* __restrict__ rowptr,
                         int* __restrict__ bsum) {
    __shared__ int sm[256];
    int t = threadIdx.x;
    int base = blockIdx.x * 1024 + t * 4;
    int v[4];
    int local = 0;
#pragma unroll
    for (int i = 0; i < 4; ++i) {
        int idx = base + i;
        v[i] = (idx < N_NODES) ? count[idx] : 0;
        local += v[i];
    }
    sm[t] = local;
    __syncthreads();
    for (int off = 1; off < 256; off <<= 1) {
        int u = (t >= off) ? sm[t - off] : 0;
        __syncthreads();
        sm[t] += u;
        __syncthreads();
    }
    int run = sm[t] - local;   // exclusive prefix within block
#pragma unroll
    for (int i = 0; i < 4; ++i) {
        int idx = base + i;
        if (idx < N_NODES) rowptr[idx] = run;
        run += v[i];
    }
    if (t == 255) bsum[blockIdx.x] = sm[255];
}

// stage B: one small block scans the 98 block sums -> exclusive boffs;
// also writes the grand total to rowptr[N_NODES].
__global__ void k_scan_b(const int* __restrict__ bsum, int* __restrict__ boffs,
                         int* __restrict__ rowptr) {
    __shared__ int sm[128];
    int t = threadIdx.x;
    int local = (t < SCAN_NBLK) ? bsum[t] : 0;
    sm[t] = local;
    __syncthreads();
    for (int off = 1; off < 128; off <<= 1) {
        int u = (t >= off) ? sm[t - off] : 0;
        __syncthreads();
        sm[t] += u;
        __syncthreads();
    }
    if (t < SCAN_NBLK) boffs[t] = sm[t] - local;
    if (t == 127) rowptr[N_NODES] = sm[127];
}

// stage C: add block offsets back into rowptr.
__global__ void k_scan_c(int* __restrict__ rowptr, const int* __restrict__ boffs) {
    int base = blockIdx.x * 1024 + threadIdx.x * 4;
    int off = boffs[blockIdx.x];
#pragma unroll
    for (int i = 0; i < 4; ++i) {
        int idx = base + i;
        if (idx < N_NODES) rowptr[idx] += off;
    }
}

// ---------------- CSR build: scatter srcs into dst order ----------------
// atomicSub reuses the histogram as a reverse-fill cursor (no extra memset).
__global__ void k_scatter(const int* __restrict__ src, const int* __restrict__ dst,
                          const int* __restrict__ rowptr, int* __restrict__ count,
                          int* __restrict__ ssrc) {
    int t = blockIdx.x * blockDim.x + threadIdx.x;
    if (t >= N_TOT) return;
    int s, d;
    if (t < N_EDGES) { s = src[t]; d = dst[t]; }
    else             { s = t - N_EDGES; d = s; }
    int old = atomicSub(&count[d], 1);
    ssrc[rowptr[d] + old - 1] = s;
}

// ---------------- layer 1: per-dst gather + softmax + ELU ---------------
// One wave (64 lanes) per dst node; lane = output channel, head = lane>>3.
// No atomics: num/den accumulate in registers over the node's edge list.
__global__ void k_gather1(const int* __restrict__ rowptr, const int* __restrict__ ssrc,
                          const float* __restrict__ h1, const float* __restrict__ as1,
                          const float* __restrict__ ad1, const float* __restrict__ b1,
                          float* __restrict__ o1) {
    int gtid = blockIdx.x * blockDim.x + threadIdx.x;
    int d    = gtid >> 6;
    int lane = threadIdx.x & 63;
    if (d >= N_NODES) return;
    int head = lane >> 3;

    int beg = rowptr[d], end = rowptr[d + 1];
    float adv = ad1[d * 8 + head];
    float num = 0.f, den = 0.f;
    for (int k = beg; k < end; ++k) {
        int s = ssrc[k];                       // wave-uniform broadcast
        float t = as1[s * 8 + head] + adv;
        t = (t > 0.f) ? t : NEG_SLOPE * t;
        float w = __expf(t);
        num += w * h1[s * 64 + lane];          // coalesced 256B per edge
        den += w;
    }
    float v = num / den + b1[lane];
    v = (v > 0.f) ? v : (__expf(v) - 1.f);     // ELU
    o1[d * 64 + lane] = v;
}

// ---------------- layer 2 node transform --------------------------------
// h2 = o1 @ W2 (64->2); as2/ad2 scalars.
__global__ void k_node2(const float* __restrict__ o1, const float* __restrict__ W2,
                        const float* __restrict__ a_src2, const float* __restrict__ a_dst2,
                        float* __restrict__ h2, float* __restrict__ as2,
                        float* __restrict__ ad2) {
    int n = blockIdx.x * blockDim.x + threadIdx.x;
    if (n >= N_NODES) return;

    float h20 = 0.f, h21 = 0.f;
    const float4* op = (const float4*)&o1[n * 64];
#pragma unroll
    for (int q = 0; q < 16; ++q) {
        float4 v = op[q];
        int c = q * 4;
        h20 += v.x * W2[(c + 0) * 2] + v.y * W2[(c + 1) * 2] +
               v.z * W2[(c + 2) * 2] + v.w * W2[(c + 3) * 2];
        h21 += v.x * W2[(c + 0) * 2 + 1] + v.y * W2[(c + 1) * 2 + 1] +
               v.z * W2[(c + 2) * 2 + 1] + v.w * W2[(c + 3) * 2 + 1];
    }
    h2[n * 2 + 0] = h20;
    h2[n * 2 + 1] = h21;
    as2[n] = h20 * a_src2[0] + h21 * a_src2[1];
    ad2[n] = h20 * a_dst2[0] + h21 * a_dst2[1];
}

// ---------------- layer 2: per-dst gather + log_softmax -----------------
// One thread per dst node.
__global__ void k_gather2(const int* __restrict__ rowptr, const int* __restrict__ ssrc,
                          const float* __restrict__ h2, const float* __restrict__ as2,
                          const float* __restrict__ ad2, const float* __restrict__ b2,
                          float* __restrict__ out) {
    int d = blockIdx.x * blockDim.x + threadIdx.x;
    if (d >= N_NODES) return;

    int beg = rowptr[d], end = rowptr[d + 1];
    float adv = ad2[d];
    float n0 = 0.f, n1 = 0.f, den = 0.f;
    const float2* h2v = (const float2*)h2;
    for (int k = beg; k < end; ++k) {
        int s = ssrc[k];
        float t = as2[s] + adv;
        t = (t > 0.f) ? t : NEG_SLOPE * t;
        float w = __expf(t);
        float2 hv = h2v[s];
        n0 += w * hv.x;
        n1 += w * hv.y;
        den += w;
    }
    float o0 = n0 / den + b2[0];
    float o1 = n1 / den + b2[1];
    float m  = fmaxf(o0, o1);
    float lse = m + __logf(__expf(o0 - m) + __expf(o1 - m));
    out[d * 2 + 0] = o0 - lse;
    out[d * 2 + 1] = o1 - lse;
}

extern "C" void kernel_launch(void* const* d_in, const int* in_sizes, int n_in,
                              void* d_out, int out_size, void* d_ws, size_t ws_size,
                              hipStream_t stream) {
    const float* x      = (const float*)d_in[0];
    const int*   ei     = (const int*)d_in[1];     // [2, E] int32
    const float* W1     = (const float*)d_in[2];
    const float* a_src1 = (const float*)d_in[3];
    const float* a_dst1 = (const float*)d_in[4];
    const float* b1     = (const float*)d_in[5];
    const float* W2     = (const float*)d_in[6];
    const float* a_src2 = (const float*)d_in[7];
    const float* a_dst2 = (const float*)d_in[8];
    const float* b2     = (const float*)d_in[9];
    float* out = (float*)d_out;

    const int* src = ei;
    const int* dst = ei + N_EDGES;

    // ---- workspace layout ----
    int*   wi     = (int*)d_ws;
    int*   count  = wi;                         // N        (histogram, then cursor)
    int*   rowptr = count + N_NODES;            // N+1
    int*   bsum   = rowptr + N_NODES + 1;       // SCAN_NBLK
    int*   boffs  = bsum + SCAN_NBLK;           // SCAN_NBLK
    int*   ssrc   = boffs + SCAN_NBLK;          // E+N
    float* wf     = (float*)(ssrc + N_TOT);
    float* h1     = wf;                         // N*64
    float* as1    = h1  + (size_t)N_NODES * 64; // N*8
    float* ad1    = as1 + (size_t)N_NODES * 8;  // N*8
    float* o1     = ad1 + (size_t)N_NODES * 8;  // N*64
    float* h2     = o1  + (size_t)N_NODES * 64; // N*2
    float* as2    = h2  + (size_t)N_NODES * 2;  // N
    float* ad2    = as2 + (size_t)N_NODES;      // N

    // zero only the histogram (everything else is fully overwritten)
    hipMemsetAsync(count, 0, (size_t)N_NODES * sizeof(int), stream);

    k_node1<<<(N_NODES * 8 + 255) / 256, 256, 0, stream>>>(x, W1, a_src1, a_dst1,
                                                           h1, as1, ad1);
    k_hist<<<(N_TOT + 255) / 256, 256, 0, stream>>>(dst, count);
    k_scan_a<<<SCAN_NBLK, 256, 0, stream>>>(count, rowptr, bsum);
    k_scan_b<<<1, 128, 0, stream>>>(bsum, boffs, rowptr);
    k_scan_c<<<SCAN_NBLK, 256, 0, stream>>>(rowptr, boffs);
    k_scatter<<<(N_TOT + 255) / 256, 256, 0, stream>>>(src, dst, rowptr, count, ssrc);
    k_gather1<<<(N_NODES * 64 + 255) / 256, 256, 0, stream>>>(rowptr, ssrc, h1, as1,
                                                              ad1, b1, o1);
    k_node2<<<(N_NODES + 255) / 256, 256, 0, stream>>>(o1, W2, a_src2, a_dst2,
                                                       h2, as2, ad2);
    k_gather2<<<(N_NODES + 255) / 256, 256, 0, stream>>>(rowptr, ssrc, h2, as2,
                                                         ad2, b2, out);
}

// Round 4
// 368.706 us; speedup vs baseline: 9.3218x; 1.3303x over previous
//
#include <hip/hip_runtime.h>
#include <hip/hip_fp16.h>
#include <math.h>
#include <stdint.h>

#define N_NODES 100000
#define N_EDGES 1600000
#define N_TOT   (N_EDGES + N_NODES)   // edges + self-loops
#define NEG_SLOPE 0.2f

#define SCAN_NBLK ((N_NODES + 1023) / 1024)   // 98 blocks, 1024 counters each

// ---------------- layer 1: node transform -------------------------------
// h1 = x @ W1 (x:[N,5], W1:[5,64]); as1/ad1 per-head attention dots.
// h1, as1 stored fp16 (gather tables); ad1 fp32 (read once per dst).
__global__ void k_node1(const float* __restrict__ x, const float* __restrict__ W1,
                        const float* __restrict__ a_src1, const float* __restrict__ a_dst1,
                        __half* __restrict__ h1h, __half* __restrict__ as1h,
                        float* __restrict__ ad1) {
    int tid  = blockIdx.x * blockDim.x + threadIdx.x;
    int n    = tid >> 3;
    int head = tid & 7;
    if (n >= N_NODES) return;

    float xv[5];
#pragma unroll
    for (int k = 0; k < 5; ++k) xv[k] = x[n * 5 + k];

    float hv[8];
    float as = 0.f, ad = 0.f;
#pragma unroll
    for (int j = 0; j < 8; ++j) {
        int c = head * 8 + j;
        float acc = 0.f;
#pragma unroll
        for (int k = 0; k < 5; ++k) acc += xv[k] * W1[k * 64 + c];
        hv[j] = acc;
        as += acc * a_src1[c];
        ad += acc * a_dst1[c];
    }
    __half2* hp = (__half2*)&h1h[n * 64 + head * 8];
#pragma unroll
    for (int j = 0; j < 4; ++j)
        hp[j] = __halves2half2(__float2half(hv[2 * j]), __float2half(hv[2 * j + 1]));
    as1h[n * 8 + head] = __float2half(as);
    ad1[n * 8 + head] = ad;
}

// ---------------- CSR build: histogram of dst ---------------------------
__global__ void k_hist(const int* __restrict__ dst, int* __restrict__ count) {
    int t = blockIdx.x * blockDim.x + threadIdx.x;
    if (t >= N_TOT) return;
    int d = (t < N_EDGES) ? dst[t] : (t - N_EDGES);
    atomicAdd(&count[d], 1);
}

// ---------------- CSR build: hierarchical exclusive scan ----------------
__global__ void k_scan_a(const int* __restrict__ count, int* __restrict__ rowptr,
                         int* __restrict__ bsum) {
    __shared__ int sm[256];
    int t = threadIdx.x;
    int base = blockIdx.x * 1024 + t * 4;
    int v[4];
    int local = 0;
#pragma unroll
    for (int i = 0; i < 4; ++i) {
        int idx = base + i;
        v[i] = (idx < N_NODES) ? count[idx] : 0;
        local += v[i];
    }
    sm[t] = local;
    __syncthreads();
    for (int off = 1; off < 256; off <<= 1) {
        int u = (t >= off) ? sm[t - off] : 0;
        __syncthreads();
        sm[t] += u;
        __syncthreads();
    }
    int run = sm[t] - local;
#pragma unroll
    for (int i = 0; i < 4; ++i) {
        int idx = base + i;
        if (idx < N_NODES) rowptr[idx] = run;
        run += v[i];
    }
    if (t == 255) bsum[blockIdx.x] = sm[255];
}

__global__ void k_scan_b(const int* __restrict__ bsum, int* __restrict__ boffs,
                         int* __restrict__ rowptr) {
    __shared__ int sm[128];
    int t = threadIdx.x;
    int local = (t < SCAN_NBLK) ? bsum[t] : 0;
    sm[t] = local;
    __syncthreads();
    for (int off = 1; off < 128; off <<= 1) {
        int u = (t >= off) ? sm[t - off] : 0;
        __syncthreads();
        sm[t] += u;
        __syncthreads();
    }
    if (t < SCAN_NBLK) boffs[t] = sm[t] - local;
    if (t == 127) rowptr[N_NODES] = sm[127];
}

__global__ void k_scan_c(int* __restrict__ rowptr, const int* __restrict__ boffs) {
    int base = blockIdx.x * 1024 + threadIdx.x * 4;
    int off = boffs[blockIdx.x];
#pragma unroll
    for (int i = 0; i < 4; ++i) {
        int idx = base + i;
        if (idx < N_NODES) rowptr[idx] += off;
    }
}

// ---------------- CSR build: scatter srcs into dst order ----------------
__global__ void k_scatter(const int* __restrict__ src, const int* __restrict__ dst,
                          const int* __restrict__ rowptr, int* __restrict__ count,
                          int* __restrict__ ssrc) {
    int t = blockIdx.x * blockDim.x + threadIdx.x;
    if (t >= N_TOT) return;
    int s, d;
    if (t < N_EDGES) { s = src[t]; d = dst[t]; }
    else             { s = t - N_EDGES; d = s; }
    int old = atomicSub(&count[d], 1);
    ssrc[rowptr[d] + old - 1] = s;
}

// ---------------- layer 1: per-dst gather + softmax + ELU ---------------
// One wave per dst node; lane = channel, head = lane>>3. Edge loop
// unrolled x4 so 4 independent h1-row gathers are in flight.
__global__ void k_gather1(const int* __restrict__ rowptr, const int* __restrict__ ssrc,
                          const __half* __restrict__ h1h, const __half* __restrict__ as1h,
                          const float* __restrict__ ad1, const float* __restrict__ b1,
                          float* __restrict__ o1) {
    int gtid = blockIdx.x * blockDim.x + threadIdx.x;
    int d    = gtid >> 6;
    int lane = threadIdx.x & 63;
    if (d >= N_NODES) return;
    int head = lane >> 3;

    int beg = rowptr[d], end = rowptr[d + 1];
    float adv = ad1[d * 8 + head];
    float num = 0.f, den = 0.f;

    int k = beg;
    for (; k + 4 <= end; k += 4) {
        int s0 = ssrc[k], s1 = ssrc[k + 1], s2 = ssrc[k + 2], s3 = ssrc[k + 3];
        float a0 = __half2float(as1h[s0 * 8 + head]);
        float a1 = __half2float(as1h[s1 * 8 + head]);
        float a2 = __half2float(as1h[s2 * 8 + head]);
        float a3 = __half2float(as1h[s3 * 8 + head]);
        float v0 = __half2float(h1h[(size_t)s0 * 64 + lane]);
        float v1 = __half2float(h1h[(size_t)s1 * 64 + lane]);
        float v2 = __half2float(h1h[(size_t)s2 * 64 + lane]);
        float v3 = __half2float(h1h[(size_t)s3 * 64 + lane]);
        float t0 = a0 + adv; t0 = (t0 > 0.f) ? t0 : NEG_SLOPE * t0;
        float t1 = a1 + adv; t1 = (t1 > 0.f) ? t1 : NEG_SLOPE * t1;
        float t2 = a2 + adv; t2 = (t2 > 0.f) ? t2 : NEG_SLOPE * t2;
        float t3 = a3 + adv; t3 = (t3 > 0.f) ? t3 : NEG_SLOPE * t3;
        float w0 = __expf(t0), w1 = __expf(t1), w2 = __expf(t2), w3 = __expf(t3);
        num += w0 * v0 + w1 * v1 + w2 * v2 + w3 * v3;
        den += w0 + w1 + w2 + w3;
    }
    for (; k < end; ++k) {
        int s = ssrc[k];
        float t = __half2float(as1h[s * 8 + head]) + adv;
        t = (t > 0.f) ? t : NEG_SLOPE * t;
        float w = __expf(t);
        num += w * __half2float(h1h[(size_t)s * 64 + lane]);
        den += w;
    }
    float v = num / den + b1[lane];
    v = (v > 0.f) ? v : (__expf(v) - 1.f);     // ELU
    o1[d * 64 + lane] = v;
}

// ---------------- layer 2 node transform --------------------------------
// rec[n] = {h2.x, h2.y, as2, ad2} — one 16B record per node.
__global__ void k_node2(const float* __restrict__ o1, const float* __restrict__ W2,
                        const float* __restrict__ a_src2, const float* __restrict__ a_dst2,
                        float4* __restrict__ rec) {
    int n = blockIdx.x * blockDim.x + threadIdx.x;
    if (n >= N_NODES) return;

    float h20 = 0.f, h21 = 0.f;
    const float4* op = (const float4*)&o1[n * 64];
#pragma unroll
    for (int q = 0; q < 16; ++q) {
        float4 v = op[q];
        int c = q * 4;
        h20 += v.x * W2[(c + 0) * 2] + v.y * W2[(c + 1) * 2] +
               v.z * W2[(c + 2) * 2] + v.w * W2[(c + 3) * 2];
        h21 += v.x * W2[(c + 0) * 2 + 1] + v.y * W2[(c + 1) * 2 + 1] +
               v.z * W2[(c + 2) * 2 + 1] + v.w * W2[(c + 3) * 2 + 1];
    }
    float as2v = h20 * a_src2[0] + h21 * a_src2[1];
    float ad2v = h20 * a_dst2[0] + h21 * a_dst2[1];
    rec[n] = make_float4(h20, h21, as2v, ad2v);
}

// ---------------- layer 2: per-dst gather + log_softmax -----------------
// 16 lanes per dst node; lanes stride the edge list, shuffle-reduce.
__global__ void k_gather2(const int* __restrict__ rowptr, const int* __restrict__ ssrc,
                          const float4* __restrict__ rec, const float* __restrict__ b2,
                          float* __restrict__ out) {
    int gtid = blockIdx.x * blockDim.x + threadIdx.x;
    int d    = gtid >> 4;
    int lane = gtid & 15;
    if (d >= N_NODES) return;

    int beg = rowptr[d], end = rowptr[d + 1];
    float adv = rec[d].w;
    float n0 = 0.f, n1 = 0.f, den = 0.f;
    for (int k = beg + lane; k < end; k += 16) {
        int s = ssrc[k];
        float4 r = rec[s];
        float t = r.z + adv;
        t = (t > 0.f) ? t : NEG_SLOPE * t;
        float w = __expf(t);
        n0 += w * r.x;
        n1 += w * r.y;
        den += w;
    }
#pragma unroll
    for (int off = 8; off; off >>= 1) {
        n0  += __shfl_xor(n0,  off, 16);
        n1  += __shfl_xor(n1,  off, 16);
        den += __shfl_xor(den, off, 16);
    }
    if (lane == 0) {
        float o0 = n0 / den + b2[0];
        float o1 = n1 / den + b2[1];
        float m  = fmaxf(o0, o1);
        float lse = m + __logf(__expf(o0 - m) + __expf(o1 - m));
        out[d * 2 + 0] = o0 - lse;
        out[d * 2 + 1] = o1 - lse;
    }
}

extern "C" void kernel_launch(void* const* d_in, const int* in_sizes, int n_in,
                              void* d_out, int out_size, void* d_ws, size_t ws_size,
                              hipStream_t stream) {
    const float* x      = (const float*)d_in[0];
    const int*   ei     = (const int*)d_in[1];     // [2, E] int32
    const float* W1     = (const float*)d_in[2];
    const float* a_src1 = (const float*)d_in[3];
    const float* a_dst1 = (const float*)d_in[4];
    const float* b1     = (const float*)d_in[5];
    const float* W2     = (const float*)d_in[6];
    const float* a_src2 = (const float*)d_in[7];
    const float* a_dst2 = (const float*)d_in[8];
    const float* b2     = (const float*)d_in[9];
    float* out = (float*)d_out;

    const int* src = ei;
    const int* dst = ei + N_EDGES;

    // ---- workspace layout ----
    int*   wi     = (int*)d_ws;
    int*   count  = wi;                         // N        (histogram, then cursor)
    int*   rowptr = count + N_NODES;            // N+1
    int*   bsum   = rowptr + N_NODES + 1;       // SCAN_NBLK
    int*   boffs  = bsum + SCAN_NBLK;           // SCAN_NBLK
    int*   ssrc   = boffs + SCAN_NBLK;          // E+N
    uintptr_t p   = ((uintptr_t)(ssrc + N_TOT) + 255) & ~(uintptr_t)255;
    float4* rec   = (float4*)p;                 // N float4 (16B aligned)
    float*  o1    = (float*)(rec + N_NODES);    // N*64
    float*  ad1   = o1 + (size_t)N_NODES * 64;  // N*8
    __half* h1h   = (__half*)(ad1 + (size_t)N_NODES * 8); // N*64 halves
    __half* as1h  = h1h + (size_t)N_NODES * 64; // N*8 halves

    // zero only the histogram (everything else is fully overwritten)
    hipMemsetAsync(count, 0, (size_t)N_NODES * sizeof(int), stream);

    k_node1<<<(N_NODES * 8 + 255) / 256, 256, 0, stream>>>(x, W1, a_src1, a_dst1,
                                                           h1h, as1h, ad1);
    k_hist<<<(N_TOT + 255) / 256, 256, 0, stream>>>(dst, count);
    k_scan_a<<<SCAN_NBLK, 256, 0, stream>>>(count, rowptr, bsum);
    k_scan_b<<<1, 128, 0, stream>>>(bsum, boffs, rowptr);
    k_scan_c<<<SCAN_NBLK, 256, 0, stream>>>(rowptr, boffs);
    k_scatter<<<(N_TOT + 255) / 256, 256, 0, stream>>>(src, dst, rowptr, count, ssrc);
    k_gather1<<<(N_NODES * 64 + 255) / 256, 256, 0, stream>>>(rowptr, ssrc, h1h, as1h,
                                                              ad1, b1, o1);
    k_node2<<<(N_NODES + 255) / 256, 256, 0, stream>>>(o1, W2, a_src2, a_dst2, rec);
    k_gather2<<<(N_NODES * 16 + 255) / 256, 256, 0, stream>>>(rowptr, ssrc, rec, b2, out);
}